// Round 1
// baseline (359.060 us; speedup 1.0000x reference)
//
#include <hip/hip_runtime.h>
#include <math.h>

static constexpr int HN = 8192;   // NUM_HIDDEN
static constexpr int IN = 8192;   // NUM_INPUTS
static constexpr float LRF = 2.0e-6f;

__device__ __forceinline__ float surrogate_f(float x) {
    const float PI = 3.14159265358979323846f;
    float px = PI * x;
    return 1.0f / (PI * fmaf(px, px, 1.0f));
}

__device__ __forceinline__ float block_reduce_f32(float v) {
#pragma unroll
    for (int off = 32; off > 0; off >>= 1) v += __shfl_down(v, off);
    __shared__ float s[4];
    if ((threadIdx.x & 63) == 0) s[threadIdx.x >> 6] = v;
    __syncthreads();
    return s[0] + s[1] + s[2] + s[3];
}

// ---- Pass A: cur = fc_w @ inp + fc_b ; LIF step (fp64 accumulation) ----
__global__ __launch_bounds__(256) void k_lif(
    const float* __restrict__ fc_w, const float* __restrict__ inp,
    const float* __restrict__ fc_b, const float* __restrict__ mem,
    float* __restrict__ out_spk, float* __restrict__ out_mem,
    float* __restrict__ ws_cur, float* __restrict__ ws_spk)
{
    const int row = blockIdx.x;
    const int t = threadIdx.x;
    const float4* __restrict__ wr = (const float4*)(fc_w + (size_t)row * IN);
    const float4* __restrict__ ip = (const float4*)inp;
    double acc = 0.0;
#pragma unroll
    for (int j = 0; j < IN / 4 / 256; ++j) {
        float4 w = wr[t + j * 256];
        float4 x = ip[t + j * 256];
        acc += (double)w.x * (double)x.x;
        acc += (double)w.y * (double)x.y;
        acc += (double)w.z * (double)x.z;
        acc += (double)w.w * (double)x.w;
    }
#pragma unroll
    for (int off = 32; off > 0; off >>= 1) acc += __shfl_down(acc, off);
    __shared__ double sacc[4];
    if ((t & 63) == 0) sacc[t >> 6] = acc;
    __syncthreads();
    if (t == 0) {
        double c = sacc[0] + sacc[1] + sacc[2] + sacc[3] + (double)fc_b[row];
        double m = 0.95 * (double)mem[row] + c;
        float spk = (m > 1.0) ? 1.0f : 0.0f;
        out_spk[row] = spk;
        ws_spk[row]  = spk;
        out_mem[row] = (float)(m - (double)spk);
        ws_cur[row]  = (float)c;
    }
}

// ---- Pass BC: blocks [0,H) handle retro_w rows, [H,2H) handle pred_w rows ----
// retro: retrodiction[i] = retro_w[i,:]·spk ; retro_w_new[i,j] = retro_w[i,j] + LR*bf*spk[i]*feedback[j]
// pred : pred_w_new[i,j] = pred_w[i,j] + LR*bf*feedback[i]*spk[j] ; feedback_new[i] = pred_w_new[i,:]·spk
__global__ __launch_bounds__(256) void k_bc(
    const float* __restrict__ retro_w, const float* __restrict__ pred_w,
    const float* __restrict__ feedback, const float* __restrict__ bfp,
    const float* __restrict__ ws_spk,
    float* __restrict__ out_pred, float* __restrict__ out_retro,
    float* __restrict__ out_fb, float* __restrict__ ws_ret)
{
    const float lrbf = LRF * bfp[0];
    const int t = threadIdx.x;
    const float4* __restrict__ spk4 = (const float4*)ws_spk;
    if (blockIdx.x < HN) {
        const int row = blockIdx.x;
        const float4* __restrict__ wr = (const float4*)(retro_w + (size_t)row * HN);
        float4* __restrict__ orow = (float4*)(out_retro + (size_t)row * HN);
        const float4* __restrict__ fb4 = (const float4*)feedback;
        const float coef = lrbf * ws_spk[row];
        float acc = 0.0f;
#pragma unroll
        for (int j = 0; j < HN / 4 / 256; ++j) {
            int idx = t + j * 256;
            float4 w = wr[idx];
            float4 s = spk4[idx];
            float4 f = fb4[idx];
            acc += w.x * s.x + w.y * s.y + w.z * s.z + w.w * s.w;
            float4 o;
            o.x = w.x + coef * f.x;
            o.y = w.y + coef * f.y;
            o.z = w.z + coef * f.z;
            o.w = w.w + coef * f.w;
            orow[idx] = o;
        }
        float r = block_reduce_f32(acc);
        if (t == 0) ws_ret[row] = r;
    } else {
        const int row = blockIdx.x - HN;
        const float4* __restrict__ wr = (const float4*)(pred_w + (size_t)row * HN);
        float4* __restrict__ orow = (float4*)(out_pred + (size_t)row * HN);
        const float coef = lrbf * feedback[row];
        float acc = 0.0f;
#pragma unroll
        for (int j = 0; j < HN / 4 / 256; ++j) {
            int idx = t + j * 256;
            float4 w = wr[idx];
            float4 s = spk4[idx];
            float4 o;
            o.x = w.x + coef * s.x;
            o.y = w.y + coef * s.y;
            o.z = w.z + coef * s.z;
            o.w = w.w + coef * s.w;
            orow[idx] = o;
            acc += o.x * s.x + o.y * s.y + o.z * s.z + o.w * s.w;
        }
        float r = block_reduce_f32(acc);
        if (t == 0) out_fb[row] = r;
    }
}

// ---- Pass D: fc_w_new[i,j] = fc_w[i,j] + a_i*inp[j] + b_i*prev_inp[j] ----
__global__ __launch_bounds__(256) void k_fc(
    const float* __restrict__ fc_w, const float* __restrict__ inp,
    const float* __restrict__ prev_inp, const float* __restrict__ feedback,
    const float* __restrict__ cur_prev, const float* __restrict__ bfp,
    const float* __restrict__ ws_cur, const float* __restrict__ ws_ret,
    float* __restrict__ out_fcw)
{
    const float bf = bfp[0];
    const int row = blockIdx.x;
    const int t = threadIdx.x;
    const float a = LRF * bf * feedback[row] * surrogate_f(ws_cur[row]);
    const float b = bf * ws_ret[row] * surrogate_f(cur_prev[row]);
    const float4* __restrict__ wr = (const float4*)(fc_w + (size_t)row * IN);
    const float4* __restrict__ ip = (const float4*)inp;
    const float4* __restrict__ pp = (const float4*)prev_inp;
    float4* __restrict__ orow = (float4*)(out_fcw + (size_t)row * IN);
#pragma unroll
    for (int j = 0; j < IN / 4 / 256; ++j) {
        int idx = t + j * 256;
        float4 w = wr[idx];
        float4 x = ip[idx];
        float4 p = pp[idx];
        float4 o;
        o.x = w.x + a * x.x + b * p.x;
        o.y = w.y + a * x.y + b * p.y;
        o.z = w.z + a * x.z + b * p.z;
        o.w = w.w + a * x.w + b * p.w;
        orow[idx] = o;
    }
}

extern "C" void kernel_launch(void* const* d_in, const int* in_sizes, int n_in,
                              void* d_out, int out_size, void* d_ws, size_t ws_size,
                              hipStream_t stream)
{
    const float* inp      = (const float*)d_in[0];
    const float* bf       = (const float*)d_in[1];
    const float* fc_w     = (const float*)d_in[2];
    const float* fc_b     = (const float*)d_in[3];
    const float* pred_w   = (const float*)d_in[4];
    const float* retro_w  = (const float*)d_in[5];
    const float* feedback = (const float*)d_in[6];
    const float* mem      = (const float*)d_in[7];
    const float* cur_prev = (const float*)d_in[8];
    const float* prev_inp = (const float*)d_in[9];

    float* out = (float*)d_out;
    float* out_spk   = out;                            // [H]
    float* out_mem   = out + HN;                       // [H]
    float* out_fcw   = out + 2 * HN;                   // [H,I]
    float* out_pred  = out_fcw + (size_t)HN * IN;      // [H,H]
    float* out_retro = out_pred + (size_t)HN * HN;     // [H,H]
    float* out_fb    = out_retro + (size_t)HN * HN;    // [H]

    float* ws = (float*)d_ws;
    float* ws_cur = ws;            // [H]
    float* ws_spk = ws + HN;       // [H]
    float* ws_ret = ws + 2 * HN;   // [H]

    k_lif<<<HN, 256, 0, stream>>>(fc_w, inp, fc_b, mem, out_spk, out_mem, ws_cur, ws_spk);
    k_bc<<<2 * HN, 256, 0, stream>>>(retro_w, pred_w, feedback, bf, ws_spk,
                                     out_pred, out_retro, out_fb, ws_ret);
    k_fc<<<HN, 256, 0, stream>>>(fc_w, inp, prev_inp, feedback, cur_prev, bf,
                                 ws_cur, ws_ret, out_fcw);
}

// Round 3
// 320.445 us; speedup vs baseline: 1.1205x; 1.1205x over previous
//
#include <hip/hip_runtime.h>
#include <math.h>

static constexpr int HN = 8192;   // NUM_HIDDEN
static constexpr int IN = 8192;   // NUM_INPUTS
static constexpr float LRF = 2.0e-6f;

typedef float f32x4 __attribute__((ext_vector_type(4)));

__device__ __forceinline__ float surrogate_f(float x) {
    const float PI = 3.14159265358979323846f;
    float px = PI * x;
    return 1.0f / (PI * fmaf(px, px, 1.0f));
}

__device__ __forceinline__ float block_reduce_f32(float v) {
#pragma unroll
    for (int off = 32; off > 0; off >>= 1) v += __shfl_down(v, off);
    __shared__ float s[4];
    if ((threadIdx.x & 63) == 0) s[threadIdx.x >> 6] = v;
    __syncthreads();
    return s[0] + s[1] + s[2] + s[3];
}

// ---- Pass A: cur = fc_w @ inp + fc_b ; LIF step (fp64 accumulation) ----
// fc_w read with NORMAL cache priority: we want it resident in L3 for the
// re-read in the fused pass (all other big streams are non-temporal).
__global__ __launch_bounds__(256) void k_lif(
    const float* __restrict__ fc_w, const float* __restrict__ inp,
    const float* __restrict__ fc_b, const float* __restrict__ mem,
    float* __restrict__ out_spk, float* __restrict__ out_mem,
    float* __restrict__ ws_cur, float* __restrict__ ws_spk)
{
    const int row = blockIdx.x;
    const int t = threadIdx.x;
    const f32x4* __restrict__ wr = (const f32x4*)(fc_w + (size_t)row * IN);
    const f32x4* __restrict__ ip = (const f32x4*)inp;
    double acc = 0.0;
#pragma unroll
    for (int j = 0; j < IN / 4 / 256; ++j) {
        f32x4 w = wr[t + j * 256];
        f32x4 x = ip[t + j * 256];
        acc += (double)w.x * (double)x.x;
        acc += (double)w.y * (double)x.y;
        acc += (double)w.z * (double)x.z;
        acc += (double)w.w * (double)x.w;
    }
#pragma unroll
    for (int off = 32; off > 0; off >>= 1) acc += __shfl_down(acc, off);
    __shared__ double sacc[4];
    if ((t & 63) == 0) sacc[t >> 6] = acc;
    __syncthreads();
    if (t == 0) {
        double c = sacc[0] + sacc[1] + sacc[2] + sacc[3] + (double)fc_b[row];
        double m = 0.95 * (double)mem[row] + c;
        float spk = (m > 1.0) ? 1.0f : 0.0f;
        out_spk[row] = spk;
        ws_spk[row]  = spk;
        out_mem[row] = (float)(m - (double)spk);
        ws_cur[row]  = (float)c;
    }
}

// ---- Fused pass: blocks [0,HN) = retro row + fc row; [HN,2HN) = pred row ----
__global__ __launch_bounds__(256) void k_fused(
    const float* __restrict__ retro_w, const float* __restrict__ pred_w,
    const float* __restrict__ fc_w, const float* __restrict__ inp,
    const float* __restrict__ prev_inp,
    const float* __restrict__ feedback, const float* __restrict__ bfp,
    const float* __restrict__ cur_prev,
    const float* __restrict__ ws_spk, const float* __restrict__ ws_cur,
    float* __restrict__ out_pred, float* __restrict__ out_retro,
    float* __restrict__ out_fcw, float* __restrict__ out_fb)
{
    const float bf = bfp[0];
    const float lrbf = LRF * bf;
    const int t = threadIdx.x;
    const f32x4* __restrict__ spk4 = (const f32x4*)ws_spk;

    if (blockIdx.x < HN) {
        const int row = blockIdx.x;
        // --- retro row: retrodiction + retro_w update ---
        const f32x4* __restrict__ wr = (const f32x4*)(retro_w + (size_t)row * HN);
        f32x4* __restrict__ orow = (f32x4*)(out_retro + (size_t)row * HN);
        const f32x4* __restrict__ fb4 = (const f32x4*)feedback;
        const float coef = lrbf * ws_spk[row];
        float acc = 0.0f;
#pragma unroll
        for (int j = 0; j < HN / 4 / 256; ++j) {
            int idx = t + j * 256;
            f32x4 w = __builtin_nontemporal_load(&wr[idx]);
            f32x4 s = spk4[idx];
            f32x4 f = fb4[idx];
            acc += w.x * s.x + w.y * s.y + w.z * s.z + w.w * s.w;
            f32x4 o;
            o.x = w.x + coef * f.x;
            o.y = w.y + coef * f.y;
            o.z = w.z + coef * f.z;
            o.w = w.w + coef * f.w;
            __builtin_nontemporal_store(o, &orow[idx]);
        }
        float retrod = block_reduce_f32(acc);
        // --- fc row (uses retrodiction from this block) ---
        const float a = lrbf * feedback[row] * surrogate_f(ws_cur[row]);
        const float b = bf * retrod * surrogate_f(cur_prev[row]);
        const f32x4* __restrict__ fwr = (const f32x4*)(fc_w + (size_t)row * IN);
        const f32x4* __restrict__ ip = (const f32x4*)inp;
        const f32x4* __restrict__ pp = (const f32x4*)prev_inp;
        f32x4* __restrict__ forow = (f32x4*)(out_fcw + (size_t)row * IN);
#pragma unroll
        for (int j = 0; j < IN / 4 / 256; ++j) {
            int idx = t + j * 256;
            f32x4 w = fwr[idx];              // normal load: hope for L3 hits
            f32x4 x = ip[idx];
            f32x4 p = pp[idx];
            f32x4 o;
            o.x = w.x + a * x.x + b * p.x;
            o.y = w.y + a * x.y + b * p.y;
            o.z = w.z + a * x.z + b * p.z;
            o.w = w.w + a * x.w + b * p.w;
            __builtin_nontemporal_store(o, &forow[idx]);
        }
    } else {
        const int row = blockIdx.x - HN;
        const f32x4* __restrict__ wr = (const f32x4*)(pred_w + (size_t)row * HN);
        f32x4* __restrict__ orow = (f32x4*)(out_pred + (size_t)row * HN);
        const float coef = lrbf * feedback[row];
        float acc = 0.0f;
#pragma unroll
        for (int j = 0; j < HN / 4 / 256; ++j) {
            int idx = t + j * 256;
            f32x4 w = __builtin_nontemporal_load(&wr[idx]);
            f32x4 s = spk4[idx];
            f32x4 o;
            o.x = w.x + coef * s.x;
            o.y = w.y + coef * s.y;
            o.z = w.z + coef * s.z;
            o.w = w.w + coef * s.w;
            __builtin_nontemporal_store(o, &orow[idx]);
            acc += o.x * s.x + o.y * s.y + o.z * s.z + o.w * s.w;
        }
        float r = block_reduce_f32(acc);
        if (t == 0) out_fb[row] = r;
    }
}

extern "C" void kernel_launch(void* const* d_in, const int* in_sizes, int n_in,
                              void* d_out, int out_size, void* d_ws, size_t ws_size,
                              hipStream_t stream)
{
    const float* inp      = (const float*)d_in[0];
    const float* bf       = (const float*)d_in[1];
    const float* fc_w     = (const float*)d_in[2];
    const float* fc_b     = (const float*)d_in[3];
    const float* pred_w   = (const float*)d_in[4];
    const float* retro_w  = (const float*)d_in[5];
    const float* feedback = (const float*)d_in[6];
    const float* mem      = (const float*)d_in[7];
    const float* cur_prev = (const float*)d_in[8];
    const float* prev_inp = (const float*)d_in[9];

    float* out = (float*)d_out;
    float* out_spk   = out;                            // [H]
    float* out_mem   = out + HN;                       // [H]
    float* out_fcw   = out + 2 * HN;                   // [H,I]
    float* out_pred  = out_fcw + (size_t)HN * IN;      // [H,H]
    float* out_retro = out_pred + (size_t)HN * HN;     // [H,H]
    float* out_fb    = out_retro + (size_t)HN * HN;    // [H]

    float* ws = (float*)d_ws;
    float* ws_cur = ws;            // [H]
    float* ws_spk = ws + HN;       // [H]

    k_lif<<<HN, 256, 0, stream>>>(fc_w, inp, fc_b, mem, out_spk, out_mem, ws_cur, ws_spk);
    k_fused<<<2 * HN, 256, 0, stream>>>(retro_w, pred_w, fc_w, inp, prev_inp,
                                        feedback, bf, cur_prev, ws_spk, ws_cur,
                                        out_pred, out_retro, out_fcw, out_fb);
}

// Round 4
// 313.041 us; speedup vs baseline: 1.1470x; 1.0236x over previous
//
#include <hip/hip_runtime.h>
#include <math.h>

static constexpr int HN = 8192;   // NUM_HIDDEN
static constexpr int IN = 8192;   // NUM_INPUTS
static constexpr float LRF = 2.0e-6f;

typedef float f32x4 __attribute__((ext_vector_type(4)));

__device__ __forceinline__ float surrogate_f(float x) {
    const float PI = 3.14159265358979323846f;
    float px = PI * x;
    return 1.0f / (PI * fmaf(px, px, 1.0f));
}

__device__ __forceinline__ float block_reduce_f32(float v) {
#pragma unroll
    for (int off = 32; off > 0; off >>= 1) v += __shfl_down(v, off);
    __shared__ float s[4];
    if ((threadIdx.x & 63) == 0) s[threadIdx.x >> 6] = v;
    __syncthreads();
    return s[0] + s[1] + s[2] + s[3];
}

// ---- Pass A: cur = fc_w @ inp + fc_b ; LIF step (fp64 accumulation) ----
// fc_w read with NORMAL cache priority: we want it resident in L3 for the
// re-read in the fused pass (all other big streams are non-temporal).
__global__ __launch_bounds__(256) void k_lif(
    const float* __restrict__ fc_w, const float* __restrict__ inp,
    const float* __restrict__ fc_b, const float* __restrict__ mem,
    float* __restrict__ out_spk, float* __restrict__ out_mem,
    float* __restrict__ ws_cur, float* __restrict__ ws_spk)
{
    const int row = blockIdx.x;
    const int t = threadIdx.x;
    const f32x4* __restrict__ wr = (const f32x4*)(fc_w + (size_t)row * IN);
    const f32x4* __restrict__ ip = (const f32x4*)inp;
    double acc = 0.0;
#pragma unroll
    for (int j = 0; j < IN / 4 / 256; ++j) {
        f32x4 w = wr[t + j * 256];
        f32x4 x = ip[t + j * 256];
        acc += (double)w.x * (double)x.x;
        acc += (double)w.y * (double)x.y;
        acc += (double)w.z * (double)x.z;
        acc += (double)w.w * (double)x.w;
    }
#pragma unroll
    for (int off = 32; off > 0; off >>= 1) acc += __shfl_down(acc, off);
    __shared__ double sacc[4];
    if ((t & 63) == 0) sacc[t >> 6] = acc;
    __syncthreads();
    if (t == 0) {
        double c = sacc[0] + sacc[1] + sacc[2] + sacc[3] + (double)fc_b[row];
        double m = 0.95 * (double)mem[row] + c;
        float spk = (m > 1.0) ? 1.0f : 0.0f;
        out_spk[row] = spk;
        ws_spk[row]  = spk;
        out_mem[row] = (float)(m - (double)spk);
        ws_cur[row]  = (float)c;
    }
}

// ---- Fused pass: blocks [0,HN) = retro row + fc row; [HN,2HN) = pred row ----
// retro block i:
//   (0) hoisted: load fc_w row i into 32 VGPRs while L3 still holds fc_w
//   (1) retrodiction_i = retro_w[i,:]·spk ; out_retro[i,:] update (nt streams)
//   (2) out_fcw[i,:] = wcache + a_i*inp + b_i*prev_inp (nt store)
// pred block i:
//   out_pred[i,:] = pred_w[i,:] + LR*bf*feedback[i]*spk[:] (nt streams)
//   out_fb[i] = out_pred[i,:]·spk
__global__ __launch_bounds__(256) void k_fused(
    const float* __restrict__ retro_w, const float* __restrict__ pred_w,
    const float* __restrict__ fc_w, const float* __restrict__ inp,
    const float* __restrict__ prev_inp,
    const float* __restrict__ feedback, const float* __restrict__ bfp,
    const float* __restrict__ cur_prev,
    const float* __restrict__ ws_spk, const float* __restrict__ ws_cur,
    float* __restrict__ out_pred, float* __restrict__ out_retro,
    float* __restrict__ out_fcw, float* __restrict__ out_fb)
{
    const float bf = bfp[0];
    const float lrbf = LRF * bf;
    const int t = threadIdx.x;
    const f32x4* __restrict__ spk4 = (const f32x4*)ws_spk;

    if (blockIdx.x < HN) {
        const int row = blockIdx.x;
        // --- (0) hoist fc_w row into registers (normal loads -> L3 hits) ---
        const f32x4* __restrict__ fwr = (const f32x4*)(fc_w + (size_t)row * IN);
        f32x4 wc0 = fwr[t + 0 * 256];
        f32x4 wc1 = fwr[t + 1 * 256];
        f32x4 wc2 = fwr[t + 2 * 256];
        f32x4 wc3 = fwr[t + 3 * 256];
        f32x4 wc4 = fwr[t + 4 * 256];
        f32x4 wc5 = fwr[t + 5 * 256];
        f32x4 wc6 = fwr[t + 6 * 256];
        f32x4 wc7 = fwr[t + 7 * 256];

        // --- (1) retro row: retrodiction + retro_w update ---
        const f32x4* __restrict__ wr = (const f32x4*)(retro_w + (size_t)row * HN);
        f32x4* __restrict__ orow = (f32x4*)(out_retro + (size_t)row * HN);
        const f32x4* __restrict__ fb4 = (const f32x4*)feedback;
        const float coef = lrbf * ws_spk[row];
        float acc = 0.0f;
#pragma unroll
        for (int j = 0; j < HN / 4 / 256; ++j) {
            int idx = t + j * 256;
            f32x4 w = __builtin_nontemporal_load(&wr[idx]);
            f32x4 s = spk4[idx];
            f32x4 f = fb4[idx];
            acc += w.x * s.x + w.y * s.y + w.z * s.z + w.w * s.w;
            f32x4 o = w + coef * f;
            __builtin_nontemporal_store(o, &orow[idx]);
        }
        float retrod = block_reduce_f32(acc);

        // --- (2) fc row from registers ---
        const float a = lrbf * feedback[row] * surrogate_f(ws_cur[row]);
        const float b = bf * retrod * surrogate_f(cur_prev[row]);
        const f32x4* __restrict__ ip = (const f32x4*)inp;
        const f32x4* __restrict__ pp = (const f32x4*)prev_inp;
        f32x4* __restrict__ forow = (f32x4*)(out_fcw + (size_t)row * IN);
        {
            int idx;
            idx = t + 0 * 256; __builtin_nontemporal_store(wc0 + a * ip[idx] + b * pp[idx], &forow[idx]);
            idx = t + 1 * 256; __builtin_nontemporal_store(wc1 + a * ip[idx] + b * pp[idx], &forow[idx]);
            idx = t + 2 * 256; __builtin_nontemporal_store(wc2 + a * ip[idx] + b * pp[idx], &forow[idx]);
            idx = t + 3 * 256; __builtin_nontemporal_store(wc3 + a * ip[idx] + b * pp[idx], &forow[idx]);
            idx = t + 4 * 256; __builtin_nontemporal_store(wc4 + a * ip[idx] + b * pp[idx], &forow[idx]);
            idx = t + 5 * 256; __builtin_nontemporal_store(wc5 + a * ip[idx] + b * pp[idx], &forow[idx]);
            idx = t + 6 * 256; __builtin_nontemporal_store(wc6 + a * ip[idx] + b * pp[idx], &forow[idx]);
            idx = t + 7 * 256; __builtin_nontemporal_store(wc7 + a * ip[idx] + b * pp[idx], &forow[idx]);
        }
    } else {
        const int row = blockIdx.x - HN;
        const f32x4* __restrict__ wr = (const f32x4*)(pred_w + (size_t)row * HN);
        f32x4* __restrict__ orow = (f32x4*)(out_pred + (size_t)row * HN);
        const float coef = lrbf * feedback[row];
        float acc = 0.0f;
#pragma unroll
        for (int j = 0; j < HN / 4 / 256; ++j) {
            int idx = t + j * 256;
            f32x4 w = __builtin_nontemporal_load(&wr[idx]);
            f32x4 s = spk4[idx];
            f32x4 o = w + coef * s;
            __builtin_nontemporal_store(o, &orow[idx]);
            acc += o.x * s.x + o.y * s.y + o.z * s.z + o.w * s.w;
        }
        float r = block_reduce_f32(acc);
        if (t == 0) out_fb[row] = r;
    }
}

extern "C" void kernel_launch(void* const* d_in, const int* in_sizes, int n_in,
                              void* d_out, int out_size, void* d_ws, size_t ws_size,
                              hipStream_t stream)
{
    const float* inp      = (const float*)d_in[0];
    const float* bf       = (const float*)d_in[1];
    const float* fc_w     = (const float*)d_in[2];
    const float* fc_b     = (const float*)d_in[3];
    const float* pred_w   = (const float*)d_in[4];
    const float* retro_w  = (const float*)d_in[5];
    const float* feedback = (const float*)d_in[6];
    const float* mem      = (const float*)d_in[7];
    const float* cur_prev = (const float*)d_in[8];
    const float* prev_inp = (const float*)d_in[9];

    float* out = (float*)d_out;
    float* out_spk   = out;                            // [H]
    float* out_mem   = out + HN;                       // [H]
    float* out_fcw   = out + 2 * HN;                   // [H,I]
    float* out_pred  = out_fcw + (size_t)HN * IN;      // [H,H]
    float* out_retro = out_pred + (size_t)HN * HN;     // [H,H]
    float* out_fb    = out_retro + (size_t)HN * HN;    // [H]

    float* ws = (float*)d_ws;
    float* ws_cur = ws;            // [H]
    float* ws_spk = ws + HN;       // [H]

    k_lif<<<HN, 256, 0, stream>>>(fc_w, inp, fc_b, mem, out_spk, out_mem, ws_cur, ws_spk);
    k_fused<<<2 * HN, 256, 0, stream>>>(retro_w, pred_w, fc_w, inp, prev_inp,
                                        feedback, bf, cur_prev, ws_spk, ws_cur,
                                        out_pred, out_retro, out_fcw, out_fb);
}